// Round 16
// baseline (105.052 us; speedup 1.0000x reference)
//
#include <hip/hip_runtime.h>
#include <hip/hip_bf16.h>
#include <math.h>

#define QSCALE 0.125f

typedef __attribute__((ext_vector_type(8))) short short8b;   // 8 bf16 (4 VGPRs)
typedef __attribute__((ext_vector_type(8))) _Float16 half8;  // 8 f16  (4 VGPRs)
typedef __attribute__((ext_vector_type(2))) _Float16 half2v; // f16x2 (1 VGPR)
typedef __attribute__((ext_vector_type(4))) float f32x4;

__device__ __forceinline__ uint pack2(float a, float b) {
    uint r;
    asm("v_cvt_pk_bf16_f32 %0, %1, %2" : "=v"(r) : "v"(a), "v"(b));
    return r;
}
__device__ __forceinline__ uint pkrtz(float a, float b) {
    uint r;
    asm("v_cvt_pkrtz_f16_f32 %0, %1, %2" : "=v"(r) : "v"(a), "v"(b));
    return r;
}
__device__ __forceinline__ half2v h2(uint u) { return __builtin_bit_cast(half2v, u); }
__device__ __forceinline__ float slogf_(float p) {
    return copysignf(log1pf(fabsf(p)), p);
}

// ------- q projection via MFMA: per (b,g,ht128) 64co x 128hw, K=64 -------
__global__ __launch_bounds__(256) void k_qproj(const float* __restrict__ x,
                                               const float* __restrict__ wq,
                                               float* __restrict__ q,
                                               short* __restrict__ qbt) {
    __shared__ uint wqh[64 * 36];    // [co][ci/2] f16 pairs
    __shared__ uint xsT[128 * 36];   // [hw][ci/2] f16 pairs
    int ht = blockIdx.x, g = blockIdx.y, b = blockIdx.z;
    int tid = threadIdx.x;
    for (int e = tid; e < 2048; e += 256) {
        int co = e >> 5, p = e & 31;
        float2 w2v = *(const float2*)&wq[(g * 64 + co) * 64 + 2 * p];
        wqh[co * 36 + p] = pkrtz(w2v.x, w2v.y);
    }
    const float* xb = x + (b * 256 + g * 64) * 1024 + ht * 128;
    for (int e = tid; e < 4096; e += 256) {
        int p = e >> 7, hw = e & 127;
        float lo = xb[(2 * p) * 1024 + hw];
        float hi = xb[(2 * p + 1) * 1024 + hw];
        xsT[hw * 36 + p] = pkrtz(lo, hi);
    }
    __syncthreads();
    int wid = tid >> 6, lane = tid & 63, lr = lane & 15, g4 = lane >> 4;
    half8 af[4][2];
    #pragma unroll
    for (int m = 0; m < 4; m++)
        #pragma unroll
        for (int s = 0; s < 2; s++)
            af[m][s] = __builtin_bit_cast(half8,
                *(const uint4*)&wqh[(m * 16 + lr) * 36 + s * 16 + g4 * 4]);
    f32x4 acc[4][2];
    #pragma unroll
    for (int m = 0; m < 4; m++)
        #pragma unroll
        for (int nt = 0; nt < 2; nt++) acc[m][nt] = (f32x4){0.f, 0.f, 0.f, 0.f};
    #pragma unroll
    for (int s = 0; s < 2; s++)
        #pragma unroll
        for (int nt = 0; nt < 2; nt++) {
            half8 bf = __builtin_bit_cast(half8,
                *(const uint4*)&xsT[(wid * 32 + nt * 16 + lr) * 36 + s * 16 + g4 * 4]);
            #pragma unroll
            for (int m = 0; m < 4; m++)
                acc[m][nt] = __builtin_amdgcn_mfma_f32_16x16x32_f16(af[m][s], bf, acc[m][nt], 0, 0, 0);
        }
    float* qb = q + (b * 256 + g * 64) * 1024 + ht * 128;
    #pragma unroll
    for (int m = 0; m < 4; m++)
        #pragma unroll
        for (int nt = 0; nt < 2; nt++) {
            int hw = wid * 32 + nt * 16 + lr;
            #pragma unroll
            for (int r = 0; r < 4; r++)
                qb[(m * 16 + g4 * 4 + r) * 1024 + hw] = acc[m][nt][r];
        }
    short* q16 = qbt + ((size_t)((b * 4 + g) * 1024 + ht * 128)) * 64;
    #pragma unroll
    for (int nt = 0; nt < 2; nt++) {
        int hw = wid * 32 + nt * 16 + lr;
        #pragma unroll
        for (int m = 0; m < 4; m++) {
            uint2 uu;
            uu.x = pack2(acc[m][nt][0] * QSCALE, acc[m][nt][1] * QSCALE);
            uu.y = pack2(acc[m][nt][2] * QSCALE, acc[m][nt][3] * QSCALE);
            *(uint2*)&q16[hw * 64 + m * 16 + g4 * 4] = uu;
        }
    }
}

// --------- offsets stage 1: depthwise conv6x6 s4 p1 + GELU ---------------
__global__ __launch_bounds__(256) void k_dw(const float* __restrict__ q,
                                            const float* __restrict__ wdw,
                                            const float* __restrict__ bdw,
                                            float* __restrict__ gdw) {
    __shared__ float qs[8 * 1024];
    __shared__ float wds[8 * 36];
    int cg = blockIdx.x, n = blockIdx.y;
    int b = n >> 2, gg = n & 3;
    int c0 = cg * 8;
    int tid = threadIdx.x;
    const float* qn = q + (b * 256 + gg * 64 + c0) * 1024;
    for (int e = tid; e < 2048; e += 256)
        ((float4*)qs)[e] = ((const float4*)qn)[e];
    for (int e = tid; e < 288; e += 256)
        wds[e] = wdw[c0 * 36 + e];
    __syncthreads();
    for (int e = tid; e < 512; e += 256) {
        int c = e >> 6, pos = e & 63;
        int oy = pos >> 3, ox = pos & 7;
        float acc = bdw[c0 + c];
        #pragma unroll
        for (int ky = 0; ky < 6; ky++) {
            int iy = oy * 4 - 1 + ky;
            if (iy < 0 || iy > 31) continue;
            #pragma unroll
            for (int kx = 0; kx < 6; kx++) {
                int ix = ox * 4 - 1 + kx;
                if (ix < 0 || ix > 31) continue;
                acc += qs[c * 1024 + iy * 32 + ix] * wds[c * 36 + ky * 6 + kx];
            }
        }
        gdw[(n * 64 + c0 + c) * 64 + pos] = acc * 0.5f * (1.f + erff(acc * 0.70710678118654752f));
    }
}

// ---- fused pre: wout-cvt + w2-cvt + pw + u0 + grid_sample + MFMA kvproj ----
__global__ __launch_bounds__(256) void k_pre(const float* __restrict__ x,
                                             const float* __restrict__ gdw,
                                             const float* __restrict__ wpw,
                                             const float* __restrict__ wk,
                                             const float* __restrict__ wv,
                                             const float* __restrict__ wout,
                                             const float* __restrict__ w2,
                                             float* __restrict__ vgs,
                                             uint* __restrict__ u0g,
                                             short* __restrict__ kob,
                                             short* __restrict__ vob,
                                             short* __restrict__ wob,
                                             uint* __restrict__ w2h) {
    __shared__ float gstage[4096];       // gdw slice [c*64+pos]
    __shared__ float kvsT[64 * 68];      // sampled kv transposed [pos][ci]
    __shared__ uint wkh[64 * 36];        // wk f16 pairs [co][ci/2]
    __shared__ uint wvh[64 * 36];
    __shared__ uint kvh[64 * 36];        // kv f16 pairs [pos][ci/2]
    __shared__ float vx_s[64], vy_s[64];
    int n = blockIdx.x, tid = threadIdx.x;
    int b = n >> 2, g = n & 3;

    {
        int e = n * 2048 + tid * 8;
        float4 f0 = *(const float4*)&wout[e];
        float4 f1 = *(const float4*)&wout[e + 4];
        uint4 u = {pack2(f0.x, f0.y), pack2(f0.z, f0.w), pack2(f1.x, f1.y), pack2(f1.z, f1.w)};
        *(uint4*)&wob[e] = u;
    }
    if (tid < 128) {
        int idx = n * 128 + tid;
        int c2 = idx >> 5, p = idx & 31;
        float2 wv2 = *(const float2*)&w2[c2 * 64 + 2 * p];
        w2h[c2 * 32 + p] = pkrtz(wv2.x, wv2.y);
    }
    for (int e = tid; e < 2048; e += 256) {
        int co = e >> 5, p = e & 31;
        float2 a = *(const float2*)&wk[(g * 64 + co) * 64 + 2 * p];
        float2 c = *(const float2*)&wv[(g * 64 + co) * 64 + 2 * p];
        wkh[co * 36 + p] = pkrtz(a.x, a.y);
        wvh[co * 36 + p] = pkrtz(c.x, c.y);
    }
    for (int e = tid; e < 1024; e += 256)
        ((float4*)gstage)[e] = ((const float4*)(gdw + n * 4096))[e];
    __syncthreads();
    if (tid < 128) {
        int o = tid >> 6, pos = tid & 63;
        float a = 0.f;
        #pragma unroll 8
        for (int c = 0; c < 64; c++) a += gstage[c * 64 + pos] * wpw[o * 64 + c];
        float off = tanhf(a) * 4.0f;
        if (o == 0) {
            int ox = pos & 7;
            float v = 2.f * ((float)ox + off) / 7.f - 1.f;
            vx_s[pos] = v;
            vgs[(n * 64 + pos) * 2] = v;
        } else {
            int oy = pos >> 3;
            float v = 2.f * ((float)oy + off) / 7.f - 1.f;
            vy_s[pos] = v;
            vgs[(n * 64 + pos) * 2 + 1] = v;
        }
    }
    __syncthreads();
    for (int e = tid; e < 2048; e += 256) {
        int ix = e >> 6, j = e & 63;
        float qx = (2.f / 31.f) * (float)ix - 1.f;
        float u = slogf_(qx - vx_s[j]);
        u0g[n * 2048 + e] = pkrtz(u, u);
    }
    for (int e = tid; e < 4096; e += 256) {
        int c = e >> 6, pos = e & 63;
        float ix = (vx_s[pos] + 1.f) * 16.f - 0.5f;
        float iy = (vy_s[pos] + 1.f) * 16.f - 0.5f;
        float x0 = floorf(ix), y0 = floorf(iy);
        float wa = (x0 + 1.f - ix) * (y0 + 1.f - iy);
        float wb = (ix - x0) * (y0 + 1.f - iy);
        float wc = (x0 + 1.f - ix) * (iy - y0);
        float wd = (ix - x0) * (iy - y0);
        const float* img = x + (b * 256 + g * 64 + c) * 1024;
        int xi = (int)x0, yi = (int)y0;
        float acc = 0.f;
        if (xi >= 0 && xi <= 31 && yi >= 0 && yi <= 31)             acc += img[yi * 32 + xi] * wa;
        if (xi + 1 >= 0 && xi + 1 <= 31 && yi >= 0 && yi <= 31)     acc += img[yi * 32 + xi + 1] * wb;
        if (xi >= 0 && xi <= 31 && yi + 1 >= 0 && yi + 1 <= 31)     acc += img[(yi + 1) * 32 + xi] * wc;
        if (xi + 1 >= 0 && xi + 1 <= 31 && yi + 1 >= 0 && yi + 1 <= 31) acc += img[(yi + 1) * 32 + xi + 1] * wd;
        kvsT[pos * 68 + c] = acc;
    }
    __syncthreads();
    for (int e = tid; e < 2048; e += 256) {
        int pos = e >> 5, p = e & 31;
        float2 v2 = *(const float2*)&kvsT[pos * 68 + 2 * p];
        kvh[pos * 36 + p] = pkrtz(v2.x, v2.y);
    }
    __syncthreads();
    int wid = tid >> 6, lane = tid & 63, lr = lane & 15, gq = lane >> 4;
    int mat = wid >> 1, cb = (wid & 1) * 32;
    const uint* wh = mat ? wvh : wkh;
    #pragma unroll
    for (int ct2 = 0; ct2 < 2; ct2++) {
        int ct = cb + ct2 * 16;
        half8 af[2];
        #pragma unroll
        for (int s = 0; s < 2; s++)
            af[s] = __builtin_bit_cast(half8, *(const uint4*)&wh[(ct + lr) * 36 + s * 16 + gq * 4]);
        #pragma unroll
        for (int nt = 0; nt < 4; nt++) {
            half8 bf[2];
            #pragma unroll
            for (int s = 0; s < 2; s++)
                bf[s] = __builtin_bit_cast(half8, *(const uint4*)&kvh[(nt * 16 + lr) * 36 + s * 16 + gq * 4]);
            f32x4 acc = {0.f, 0.f, 0.f, 0.f};
            acc = __builtin_amdgcn_mfma_f32_16x16x32_f16(af[0], bf[0], acc, 0, 0, 0);
            acc = __builtin_amdgcn_mfma_f32_16x16x32_f16(af[1], bf[1], acc, 0, 0, 0);
            if (mat == 0) {
                uint2 uu = {pack2(acc[0], acc[1]), pack2(acc[2], acc[3])};
                *(uint2*)&kob[n * 4096 + (nt * 16 + lr) * 64 + ct + gq * 4] = uu;
            } else {
                #pragma unroll
                for (int r = 0; r < 4; r++)
                    vob[n * 4096 + (ct + gq * 4 + r) * 64 + nt * 16 + lr] = (short)pack2(acc[r], acc[r]);
            }
        }
    }
}

// ---- CPB bias MLP + fused attention. Block (iy,n), 512 thr / 8 waves. ----
// Main loop: each wave computes bias for 4 ix into LDS (2x the resident
// waves of the 256-thr version -> better latency hiding). Tail: waves 0,1.
__global__ __launch_bounds__(512) void k_cpb(const float* __restrict__ vgs,
                                             const uint* __restrict__ u0g,
                                             const float* __restrict__ w1,
                                             const float* __restrict__ b1,
                                             const uint* __restrict__ w2h,
                                             const float* __restrict__ b2,
                                             const float* __restrict__ w3,
                                             const float* __restrict__ b3,
                                             const short* __restrict__ qbt,
                                             const short* __restrict__ kob,
                                             const short* __restrict__ vob,
                                             short* __restrict__ attb) {
    __shared__ uint Q1p[64 * 36];    // [j][k-pair] f16x2, stride 36
    __shared__ uint u0p[32 * 64];    // [ix][j] f16x2 (full iy row)
    __shared__ uint w2s[64 * 36];    // [c2][k-pair] f16x2, stride 36
    __shared__ float u1t[64];
    __shared__ uint w1ps[32];
    __shared__ float w3s[64];
    __shared__ float b2s[64];
    __shared__ float biasS[32 * 68]; // bias [ix][j]; halves reused as attn scratch
    int iy = blockIdx.x, n = blockIdx.y, tid = threadIdx.x;
    float qy = 2.f * (float)iy / 31.f - 1.f;

    if (tid < 64) u1t[tid] = slogf_(qy - vgs[(n << 7) + tid * 2 + 1]);
    if (tid >= 64 && tid < 96) {
        int p = tid - 64;
        int s = p >> 4, gg = (p >> 2) & 3, pp = p & 3;
        int k = s * 32 + gg * 8 + 2 * pp;
        w1ps[p] = pkrtz(w1[2 * k], w1[2 * k + 2]);
    }
    if (tid >= 128 && tid < 192) w3s[tid - 128] = w3[tid - 128];
    if (tid >= 192 && tid < 256) b2s[tid - 192] = b2[tid - 192];
    __syncthreads();
    for (int e = tid; e < 2048; e += 512) {
        int j = e >> 5, pp = e & 31;
        int k = pp * 2;
        float lo = fmaf(w1[2 * k + 1], u1t[j], b1[k]);
        float hi = fmaf(w1[2 * k + 3], u1t[j], b1[k + 1]);
        Q1p[j * 36 + pp] = pkrtz(lo, hi);
    }
    for (int e = tid; e < 2048; e += 512)
        w2s[(e >> 5) * 36 + (e & 31)] = w2h[e];
    for (int e = tid; e < 2048; e += 512)
        u0p[e] = u0g[n * 2048 + e];

    int wid = tid >> 6, lane = tid & 63, lr = lane & 15, g = lane >> 4;
    float b3v = b3[0];
    __syncthreads();

    const half2v hz = {(_Float16)0, (_Float16)0};
    for (int ii = 0; ii < 4; ii++) {
        int ixl = wid * 4 + ii;
        #pragma unroll
        for (int nt = 0; nt < 4; nt++) {
            half2v u0v = h2(u0p[ixl * 64 + nt * 16 + lr]);
            const uint* q1p = &Q1p[(nt * 16 + lr) * 36];
            half8 bfr[2];
            #pragma unroll
            for (int s = 0; s < 2; s++) {
                uint4 q4 = *(const uint4*)&q1p[s * 16 + g * 4];
                uint4 wp4 = *(const uint4*)&w1ps[s * 16 + g * 4];
                half2v h0 = __builtin_elementwise_max(h2(wp4.x) * u0v + h2(q4.x), hz);
                half2v h1v = __builtin_elementwise_max(h2(wp4.y) * u0v + h2(q4.y), hz);
                half2v h2v_ = __builtin_elementwise_max(h2(wp4.z) * u0v + h2(q4.z), hz);
                half2v h3 = __builtin_elementwise_max(h2(wp4.w) * u0v + h2(q4.w), hz);
                uint4 hb = {__builtin_bit_cast(uint, h0), __builtin_bit_cast(uint, h1v),
                            __builtin_bit_cast(uint, h2v_), __builtin_bit_cast(uint, h3)};
                bfr[s] = __builtin_bit_cast(half8, hb);
            }
            f32x4 acc[4];
            #pragma unroll
            for (int m = 0; m < 4; m++) {
                half8 w2f0 = __builtin_bit_cast(half8,
                    *(const uint4*)&w2s[(m * 16 + lr) * 36 + g * 4]);
                f32x4 cseed = *(const f32x4*)&b2s[m * 16 + g * 4];
                acc[m] = __builtin_amdgcn_mfma_f32_16x16x32_f16(w2f0, bfr[0], cseed, 0, 0, 0);
            }
            #pragma unroll
            for (int m = 0; m < 4; m++) {
                half8 w2f1 = __builtin_bit_cast(half8,
                    *(const uint4*)&w2s[(m * 16 + lr) * 36 + 16 + g * 4]);
                acc[m] = __builtin_amdgcn_mfma_f32_16x16x32_f16(w2f1, bfr[1], acc[m], 0, 0, 0);
            }
            f32x4 tv = {0.f, 0.f, 0.f, 0.f};
            #pragma unroll
            for (int m = 0; m < 4; m++) {
                f32x4 r = __builtin_elementwise_max(acc[m], (f32x4){0.f, 0.f, 0.f, 0.f});
                f32x4 w3m = *(const f32x4*)&w3s[m * 16 + g * 4];
                tv += w3m * r;
            }
            float t = (tv[0] + tv[1]) + (tv[2] + tv[3]);
            t += __shfl_xor(t, 16);
            t += __shfl_xor(t, 32);
            if (g == nt) biasS[ixl * 68 + lane] = t + b3v;
        }
    }
    __syncthreads();

    // ---------------- fused attention (waves 0 and 1) ---------------------
    if (wid < 2) {
        int lb = wid * 16;                 // local row base
        float* P = &biasS[lb * 68];        // 16*68 scratch
        int i0w = iy * 32 + lb;
        const short* kb = kob + n * 4096;
        const short* vb = vob + n * 4096;
        const short* qb = qbt + ((size_t)n * 1024 + i0w + lr) * 64;
        short8b qf[2];
        qf[0] = *(const short8b*)&qb[g * 8];
        qf[1] = *(const short8b*)&qb[32 + g * 8];
        float bv[4][4];
        #pragma unroll
        for (int r = 0; r < 4; r++)
            #pragma unroll
            for (int nt = 0; nt < 4; nt++)
                bv[r][nt] = biasS[(lb + g * 4 + r) * 68 + nt * 16 + lr];

        f32x4 acc[4];
        #pragma unroll
        for (int nt = 0; nt < 4; nt++) {
            short8b kf0 = *(const short8b*)&kb[(nt * 16 + lr) * 64 + g * 8];
            short8b kf1 = *(const short8b*)&kb[(nt * 16 + lr) * 64 + 32 + g * 8];
            acc[nt] = (f32x4){0.f, 0.f, 0.f, 0.f};
            acc[nt] = __builtin_amdgcn_mfma_f32_16x16x32_bf16(qf[0], kf0, acc[nt], 0, 0, 0);
            acc[nt] = __builtin_amdgcn_mfma_f32_16x16x32_bf16(qf[1], kf1, acc[nt], 0, 0, 0);
        }
        #pragma unroll
        for (int r = 0; r < 4; r++) {
            float s0 = acc[0][r] + bv[r][0], s1 = acc[1][r] + bv[r][1];
            float s2 = acc[2][r] + bv[r][2], s3 = acc[3][r] + bv[r][3];
            float m = fmaxf(fmaxf(s0, s1), fmaxf(s2, s3));
            m = fmaxf(m, __shfl_xor(m, 1));
            m = fmaxf(m, __shfl_xor(m, 2));
            m = fmaxf(m, __shfl_xor(m, 4));
            m = fmaxf(m, __shfl_xor(m, 8));
            float e0 = __expf(s0 - m), e1 = __expf(s1 - m);
            float e2 = __expf(s2 - m), e3 = __expf(s3 - m);
            float sum = (e0 + e1) + (e2 + e3);
            sum += __shfl_xor(sum, 1);
            sum += __shfl_xor(sum, 2);
            sum += __shfl_xor(sum, 4);
            sum += __shfl_xor(sum, 8);
            float inv = 1.f / sum;
            int row = g * 4 + r;
            P[row * 68 + lr]      = e0 * inv;
            P[row * 68 + 16 + lr] = e1 * inv;
            P[row * 68 + 32 + lr] = e2 * inv;
            P[row * 68 + 48 + lr] = e3 * inv;
        }
        const float* pr = &P[lr * 68];
        float4 a0 = *(float4*)&pr[g * 8];
        float4 a1 = *(float4*)&pr[g * 8 + 4];
        float4 a2 = *(float4*)&pr[32 + g * 8];
        float4 a3 = *(float4*)&pr[32 + g * 8 + 4];
        uint4 up0 = {pack2(a0.x, a0.y), pack2(a0.z, a0.w), pack2(a1.x, a1.y), pack2(a1.z, a1.w)};
        uint4 up1 = {pack2(a2.x, a2.y), pack2(a2.z, a2.w), pack2(a3.x, a3.y), pack2(a3.z, a3.w)};
        short8b pf0 = __builtin_bit_cast(short8b, up0);
        short8b pf1 = __builtin_bit_cast(short8b, up1);

        f32x4 oacc[4];
        #pragma unroll
        for (int nt = 0; nt < 4; nt++) {
            short8b vf0 = *(const short8b*)&vb[(nt * 16 + lr) * 64 + g * 8];
            short8b vf1 = *(const short8b*)&vb[(nt * 16 + lr) * 64 + 32 + g * 8];
            oacc[nt] = (f32x4){0.f, 0.f, 0.f, 0.f};
            oacc[nt] = __builtin_amdgcn_mfma_f32_16x16x32_bf16(pf0, vf0, oacc[nt], 0, 0, 0);
            oacc[nt] = __builtin_amdgcn_mfma_f32_16x16x32_bf16(pf1, vf1, oacc[nt], 0, 0, 0);
        }
        #pragma unroll
        for (int nt = 0; nt < 4; nt++)
            #pragma unroll
            for (int r = 0; r < 4; r++)
                P[(nt * 16 + lr) * 17 + g * 4 + r] = oacc[nt][r];
        int il = lane >> 2, dq = lane & 3;
        uint ub[8];
        #pragma unroll
        for (int t = 0; t < 8; t++) {
            float lo = P[(dq * 16 + 2 * t) * 17 + il];
            float hi = P[(dq * 16 + 2 * t + 1) * 17 + il];
            ub[t] = pack2(lo, hi);
        }
        int b_ = n >> 2, h_ = n & 3;
        short* op = attb + ((size_t)(b_ * 1024 + i0w + il)) * 256 + h_ * 64 + dq * 16;
        uint4 s0v = {ub[0], ub[1], ub[2], ub[3]};
        uint4 s1v = {ub[4], ub[5], ub[6], ub[7]};
        ((uint4*)op)[0] = s0v;
        ((uint4*)op)[1] = s1v;
    }
}

// ------------- output projection via MFMA: C[(b,hw)][co], K=256 -----------
__global__ __launch_bounds__(256) void k_outproj(const short* __restrict__ attb,
                                                 const short* __restrict__ wob,
                                                 const float* __restrict__ bout,
                                                 float* __restrict__ y) {
    int rt = blockIdx.x;             // 256: b = rt>>5, hw-tile of 32
    int ct = blockIdx.y;             // 2
    int tid = threadIdx.x, wid = tid >> 6, lane = tid & 63, lr = lane & 15, g = lane >> 4;
    int wr = wid >> 1, wc = wid & 1;
    int b = rt >> 5;
    int hw0 = (rt & 31) * 32 + wr * 16;
    int cobase = ct * 128 + wc * 64;
    const short* arow = attb + ((size_t)(b * 1024) + hw0) * 256;
    const short* brow = wob + (size_t)cobase * 256;

    f32x4 acc[4];
    #pragma unroll
    for (int nn = 0; nn < 4; nn++) acc[nn] = (f32x4){0.f, 0.f, 0.f, 0.f};
    #pragma unroll
    for (int s = 0; s < 8; s++) {
        short8b af = *(const short8b*)&arow[lr * 256 + s * 32 + g * 8];
        #pragma unroll
        for (int nn = 0; nn < 4; nn++) {
            short8b bf = *(const short8b*)&brow[(nn * 16 + lr) * 256 + s * 32 + g * 8];
            acc[nn] = __builtin_amdgcn_mfma_f32_16x16x32_bf16(af, bf, acc[nn], 0, 0, 0);
        }
    }
    #pragma unroll
    for (int nn = 0; nn < 4; nn++) {
        int co = cobase + nn * 16 + lr;
        float bo = bout[co];
        float4 o = {acc[nn][0] + bo, acc[nn][1] + bo, acc[nn][2] + bo, acc[nn][3] + bo};
        *(float4*)&y[(size_t)b * 262144 + (size_t)co * 1024 + hw0 + g * 4] = o;
    }
}

extern "C" void kernel_launch(void* const* d_in, const int* in_sizes, int n_in,
                              void* d_out, int out_size, void* d_ws, size_t ws_size,
                              hipStream_t stream) {
    const float* x    = (const float*)d_in[0];
    const float* wq   = (const float*)d_in[1];
    const float* wk   = (const float*)d_in[2];
    const float* wv   = (const float*)d_in[3];
    const float* wdw  = (const float*)d_in[4];
    const float* bdw  = (const float*)d_in[5];
    const float* wpw  = (const float*)d_in[6];
    const float* cw1  = (const float*)d_in[7];
    const float* cb1  = (const float*)d_in[8];
    const float* cw2  = (const float*)d_in[9];
    const float* cb2  = (const float*)d_in[10];
    const float* cw3  = (const float*)d_in[11];
    const float* cb3  = (const float*)d_in[12];
    const float* wout = (const float*)d_in[13];
    const float* bout = (const float*)d_in[14];
    float* y  = (float*)d_out;
    float* ws = (float*)d_ws;

    float* q    = ws;                          // 8MB f32 (dead after k_dw)
    short* attb = (short*)ws;                  // alias: bf16 attn out [b*hw][ci]
    float* vgs  = ws + 4325376;
    short* qbt  = (short*)(ws + 4329472);
    short* kob  = (short*)(ws + 5378048);
    short* vob  = (short*)(ws + 5443584);
    float* gdw  = ws + 5509120;
    short* wob  = (short*)(ws + 5640192);      // 65536 bf16
    uint*  u0g  = (uint*)(ws + 5672960);       // 65536 uint (f16x2 u0 table)
    uint*  w2h  = (uint*)(ws + 5738496);       // 2048 uint (f16x2 W2)

    k_qproj  <<<dim3(8, 4, 8),  256, 0, stream>>>(x, wq, q, qbt);
    k_dw     <<<dim3(8, 32),    256, 0, stream>>>(q, wdw, bdw, gdw);
    k_pre    <<<32,             256, 0, stream>>>(x, gdw, wpw, wk, wv, wout, cw2,
                                                  vgs, u0g, kob, vob, wob, w2h);
    k_cpb    <<<dim3(32, 32),   512, 0, stream>>>(vgs, u0g, cw1, cb1, w2h, cb2, cw3, cb3,
                                                  qbt, kob, vob, attb);
    k_outproj<<<dim3(256, 2),   256, 0, stream>>>(attb, wob, bout, y);
}

// Round 17
// 95.654 us; speedup vs baseline: 1.0983x; 1.0983x over previous
//
#include <hip/hip_runtime.h>
#include <hip/hip_bf16.h>
#include <math.h>

#define QSCALE 0.125f

typedef __attribute__((ext_vector_type(8))) short short8b;   // 8 bf16 (4 VGPRs)
typedef __attribute__((ext_vector_type(8))) _Float16 half8;  // 8 f16  (4 VGPRs)
typedef __attribute__((ext_vector_type(2))) _Float16 half2v; // f16x2 (1 VGPR)
typedef __attribute__((ext_vector_type(4))) float f32x4;

__device__ __forceinline__ uint pack2(float a, float b) {
    uint r;
    asm("v_cvt_pk_bf16_f32 %0, %1, %2" : "=v"(r) : "v"(a), "v"(b));
    return r;
}
__device__ __forceinline__ uint pkrtz(float a, float b) {
    uint r;
    asm("v_cvt_pkrtz_f16_f32 %0, %1, %2" : "=v"(r) : "v"(a), "v"(b));
    return r;
}
__device__ __forceinline__ half2v h2(uint u) { return __builtin_bit_cast(half2v, u); }
__device__ __forceinline__ float slogf_(float p) {
    return copysignf(log1pf(fabsf(p)), p);
}

// ------- q projection via MFMA: per (b,g,ht128) 64co x 128hw, K=64 -------
__global__ __launch_bounds__(256) void k_qproj(const float* __restrict__ x,
                                               const float* __restrict__ wq,
                                               float* __restrict__ q,
                                               short* __restrict__ qbt) {
    __shared__ uint wqh[64 * 36];    // [co][ci/2] f16 pairs
    __shared__ uint xsT[128 * 36];   // [hw][ci/2] f16 pairs
    int ht = blockIdx.x, g = blockIdx.y, b = blockIdx.z;
    int tid = threadIdx.x;
    for (int e = tid; e < 2048; e += 256) {
        int co = e >> 5, p = e & 31;
        float2 w2v = *(const float2*)&wq[(g * 64 + co) * 64 + 2 * p];
        wqh[co * 36 + p] = pkrtz(w2v.x, w2v.y);
    }
    const float* xb = x + (b * 256 + g * 64) * 1024 + ht * 128;
    for (int e = tid; e < 4096; e += 256) {
        int p = e >> 7, hw = e & 127;
        float lo = xb[(2 * p) * 1024 + hw];
        float hi = xb[(2 * p + 1) * 1024 + hw];
        xsT[hw * 36 + p] = pkrtz(lo, hi);
    }
    __syncthreads();
    int wid = tid >> 6, lane = tid & 63, lr = lane & 15, g4 = lane >> 4;
    half8 af[4][2];
    #pragma unroll
    for (int m = 0; m < 4; m++)
        #pragma unroll
        for (int s = 0; s < 2; s++)
            af[m][s] = __builtin_bit_cast(half8,
                *(const uint4*)&wqh[(m * 16 + lr) * 36 + s * 16 + g4 * 4]);
    f32x4 acc[4][2];
    #pragma unroll
    for (int m = 0; m < 4; m++)
        #pragma unroll
        for (int nt = 0; nt < 2; nt++) acc[m][nt] = (f32x4){0.f, 0.f, 0.f, 0.f};
    #pragma unroll
    for (int s = 0; s < 2; s++)
        #pragma unroll
        for (int nt = 0; nt < 2; nt++) {
            half8 bf = __builtin_bit_cast(half8,
                *(const uint4*)&xsT[(wid * 32 + nt * 16 + lr) * 36 + s * 16 + g4 * 4]);
            #pragma unroll
            for (int m = 0; m < 4; m++)
                acc[m][nt] = __builtin_amdgcn_mfma_f32_16x16x32_f16(af[m][s], bf, acc[m][nt], 0, 0, 0);
        }
    float* qb = q + (b * 256 + g * 64) * 1024 + ht * 128;
    #pragma unroll
    for (int m = 0; m < 4; m++)
        #pragma unroll
        for (int nt = 0; nt < 2; nt++) {
            int hw = wid * 32 + nt * 16 + lr;
            #pragma unroll
            for (int r = 0; r < 4; r++)
                qb[(m * 16 + g4 * 4 + r) * 1024 + hw] = acc[m][nt][r];
        }
    short* q16 = qbt + ((size_t)((b * 4 + g) * 1024 + ht * 128)) * 64;
    #pragma unroll
    for (int nt = 0; nt < 2; nt++) {
        int hw = wid * 32 + nt * 16 + lr;
        #pragma unroll
        for (int m = 0; m < 4; m++) {
            uint2 uu;
            uu.x = pack2(acc[m][nt][0] * QSCALE, acc[m][nt][1] * QSCALE);
            uu.y = pack2(acc[m][nt][2] * QSCALE, acc[m][nt][3] * QSCALE);
            *(uint2*)&q16[hw * 64 + m * 16 + g4 * 4] = uu;
        }
    }
}

// --------- offsets stage 1: depthwise conv6x6 s4 p1 + GELU ---------------
__global__ __launch_bounds__(256) void k_dw(const float* __restrict__ q,
                                            const float* __restrict__ wdw,
                                            const float* __restrict__ bdw,
                                            float* __restrict__ gdw) {
    __shared__ float qs[8 * 1024];
    __shared__ float wds[8 * 36];
    int cg = blockIdx.x, n = blockIdx.y;
    int b = n >> 2, gg = n & 3;
    int c0 = cg * 8;
    int tid = threadIdx.x;
    const float* qn = q + (b * 256 + gg * 64 + c0) * 1024;
    for (int e = tid; e < 2048; e += 256)
        ((float4*)qs)[e] = ((const float4*)qn)[e];
    for (int e = tid; e < 288; e += 256)
        wds[e] = wdw[c0 * 36 + e];
    __syncthreads();
    for (int e = tid; e < 512; e += 256) {
        int c = e >> 6, pos = e & 63;
        int oy = pos >> 3, ox = pos & 7;
        float acc = bdw[c0 + c];
        #pragma unroll
        for (int ky = 0; ky < 6; ky++) {
            int iy = oy * 4 - 1 + ky;
            if (iy < 0 || iy > 31) continue;
            #pragma unroll
            for (int kx = 0; kx < 6; kx++) {
                int ix = ox * 4 - 1 + kx;
                if (ix < 0 || ix > 31) continue;
                acc += qs[c * 1024 + iy * 32 + ix] * wds[c * 36 + ky * 6 + kx];
            }
        }
        gdw[(n * 64 + c0 + c) * 64 + pos] = acc * 0.5f * (1.f + erff(acc * 0.70710678118654752f));
    }
}

// ---- fused pre: wout-cvt + w2-cvt + pw + u0 + grid_sample + MFMA kvproj ----
__global__ __launch_bounds__(256) void k_pre(const float* __restrict__ x,
                                             const float* __restrict__ gdw,
                                             const float* __restrict__ wpw,
                                             const float* __restrict__ wk,
                                             const float* __restrict__ wv,
                                             const float* __restrict__ wout,
                                             const float* __restrict__ w2,
                                             float* __restrict__ vgs,
                                             uint* __restrict__ u0g,
                                             short* __restrict__ kob,
                                             short* __restrict__ vob,
                                             short* __restrict__ wob,
                                             uint* __restrict__ w2h) {
    __shared__ float gstage[4096];       // gdw slice [c*64+pos]
    __shared__ float kvsT[64 * 68];      // sampled kv transposed [pos][ci]
    __shared__ uint wkh[64 * 36];        // wk f16 pairs [co][ci/2]
    __shared__ uint wvh[64 * 36];
    __shared__ uint kvh[64 * 36];        // kv f16 pairs [pos][ci/2]
    __shared__ float vx_s[64], vy_s[64];
    int n = blockIdx.x, tid = threadIdx.x;
    int b = n >> 2, g = n & 3;

    {
        int e = n * 2048 + tid * 8;
        float4 f0 = *(const float4*)&wout[e];
        float4 f1 = *(const float4*)&wout[e + 4];
        uint4 u = {pack2(f0.x, f0.y), pack2(f0.z, f0.w), pack2(f1.x, f1.y), pack2(f1.z, f1.w)};
        *(uint4*)&wob[e] = u;
    }
    if (tid < 128) {
        int idx = n * 128 + tid;
        int c2 = idx >> 5, p = idx & 31;
        float2 wv2 = *(const float2*)&w2[c2 * 64 + 2 * p];
        w2h[c2 * 32 + p] = pkrtz(wv2.x, wv2.y);
    }
    for (int e = tid; e < 2048; e += 256) {
        int co = e >> 5, p = e & 31;
        float2 a = *(const float2*)&wk[(g * 64 + co) * 64 + 2 * p];
        float2 c = *(const float2*)&wv[(g * 64 + co) * 64 + 2 * p];
        wkh[co * 36 + p] = pkrtz(a.x, a.y);
        wvh[co * 36 + p] = pkrtz(c.x, c.y);
    }
    for (int e = tid; e < 1024; e += 256)
        ((float4*)gstage)[e] = ((const float4*)(gdw + n * 4096))[e];
    __syncthreads();
    if (tid < 128) {
        int o = tid >> 6, pos = tid & 63;
        float a = 0.f;
        #pragma unroll 8
        for (int c = 0; c < 64; c++) a += gstage[c * 64 + pos] * wpw[o * 64 + c];
        float off = tanhf(a) * 4.0f;
        if (o == 0) {
            int ox = pos & 7;
            float v = 2.f * ((float)ox + off) / 7.f - 1.f;
            vx_s[pos] = v;
            vgs[(n * 64 + pos) * 2] = v;
        } else {
            int oy = pos >> 3;
            float v = 2.f * ((float)oy + off) / 7.f - 1.f;
            vy_s[pos] = v;
            vgs[(n * 64 + pos) * 2 + 1] = v;
        }
    }
    __syncthreads();
    for (int e = tid; e < 2048; e += 256) {
        int ix = e >> 6, j = e & 63;
        float qx = (2.f / 31.f) * (float)ix - 1.f;
        float u = slogf_(qx - vx_s[j]);
        u0g[n * 2048 + e] = pkrtz(u, u);
    }
    for (int e = tid; e < 4096; e += 256) {
        int c = e >> 6, pos = e & 63;
        float ix = (vx_s[pos] + 1.f) * 16.f - 0.5f;
        float iy = (vy_s[pos] + 1.f) * 16.f - 0.5f;
        float x0 = floorf(ix), y0 = floorf(iy);
        float wa = (x0 + 1.f - ix) * (y0 + 1.f - iy);
        float wb = (ix - x0) * (y0 + 1.f - iy);
        float wc = (x0 + 1.f - ix) * (iy - y0);
        float wd = (ix - x0) * (iy - y0);
        const float* img = x + (b * 256 + g * 64 + c) * 1024;
        int xi = (int)x0, yi = (int)y0;
        float acc = 0.f;
        if (xi >= 0 && xi <= 31 && yi >= 0 && yi <= 31)             acc += img[yi * 32 + xi] * wa;
        if (xi + 1 >= 0 && xi + 1 <= 31 && yi >= 0 && yi <= 31)     acc += img[yi * 32 + xi + 1] * wb;
        if (xi >= 0 && xi <= 31 && yi + 1 >= 0 && yi + 1 <= 31)     acc += img[(yi + 1) * 32 + xi] * wc;
        if (xi + 1 >= 0 && xi + 1 <= 31 && yi + 1 >= 0 && yi + 1 <= 31) acc += img[(yi + 1) * 32 + xi + 1] * wd;
        kvsT[pos * 68 + c] = acc;
    }
    __syncthreads();
    for (int e = tid; e < 2048; e += 256) {
        int pos = e >> 5, p = e & 31;
        float2 v2 = *(const float2*)&kvsT[pos * 68 + 2 * p];
        kvh[pos * 36 + p] = pkrtz(v2.x, v2.y);
    }
    __syncthreads();
    int wid = tid >> 6, lane = tid & 63, lr = lane & 15, gq = lane >> 4;
    int mat = wid >> 1, cb = (wid & 1) * 32;
    const uint* wh = mat ? wvh : wkh;
    #pragma unroll
    for (int ct2 = 0; ct2 < 2; ct2++) {
        int ct = cb + ct2 * 16;
        half8 af[2];
        #pragma unroll
        for (int s = 0; s < 2; s++)
            af[s] = __builtin_bit_cast(half8, *(const uint4*)&wh[(ct + lr) * 36 + s * 16 + gq * 4]);
        #pragma unroll
        for (int nt = 0; nt < 4; nt++) {
            half8 bf[2];
            #pragma unroll
            for (int s = 0; s < 2; s++)
                bf[s] = __builtin_bit_cast(half8, *(const uint4*)&kvh[(nt * 16 + lr) * 36 + s * 16 + gq * 4]);
            f32x4 acc = {0.f, 0.f, 0.f, 0.f};
            acc = __builtin_amdgcn_mfma_f32_16x16x32_f16(af[0], bf[0], acc, 0, 0, 0);
            acc = __builtin_amdgcn_mfma_f32_16x16x32_f16(af[1], bf[1], acc, 0, 0, 0);
            if (mat == 0) {
                uint2 uu = {pack2(acc[0], acc[1]), pack2(acc[2], acc[3])};
                *(uint2*)&kob[n * 4096 + (nt * 16 + lr) * 64 + ct + gq * 4] = uu;
            } else {
                #pragma unroll
                for (int r = 0; r < 4; r++)
                    vob[n * 4096 + (ct + gq * 4 + r) * 64 + nt * 16 + lr] = (short)pack2(acc[r], acc[r]);
            }
        }
    }
}

// ---- CPB bias MLP + fused attention. Block (iy,n), 256 thr / 4 waves. ----
// W2 fragments in registers (R13 layout) -> LDS ~27KB -> 5 blocks/CU.
__global__ __launch_bounds__(256) void k_cpb(const float* __restrict__ vgs,
                                             const uint* __restrict__ u0g,
                                             const float* __restrict__ w1,
                                             const float* __restrict__ b1,
                                             const uint* __restrict__ w2h,
                                             const float* __restrict__ b2,
                                             const float* __restrict__ w3,
                                             const float* __restrict__ b3,
                                             const short* __restrict__ qbt,
                                             const short* __restrict__ kob,
                                             const short* __restrict__ vob,
                                             short* __restrict__ attb) {
    __shared__ uint Q1p[64 * 36];    // [j][k-pair] f16x2, stride 36
    __shared__ uint u0p[32 * 64];    // [ix][j] f16x2 (full iy row)
    __shared__ float u1t[64];
    __shared__ uint w1ps[32];
    __shared__ float w3s[64];
    __shared__ float b2s[64];
    __shared__ float biasS[32 * 68]; // bias [ix][j]; halves reused as attn scratch
    int iy = blockIdx.x, n = blockIdx.y, tid = threadIdx.x;
    float qy = 2.f * (float)iy / 31.f - 1.f;

    if (tid < 64) u1t[tid] = slogf_(qy - vgs[(n << 7) + tid * 2 + 1]);
    if (tid >= 64 && tid < 96) {
        int p = tid - 64;
        int s = p >> 4, gg = (p >> 2) & 3, pp = p & 3;
        int k = s * 32 + gg * 8 + 2 * pp;
        w1ps[p] = pkrtz(w1[2 * k], w1[2 * k + 2]);
    }
    if (tid >= 128 && tid < 192) w3s[tid - 128] = w3[tid - 128];
    if (tid >= 192) b2s[tid - 192] = b2[tid - 192];
    __syncthreads();
    for (int e = tid; e < 2048; e += 256) {
        int j = e >> 5, pp = e & 31;
        int k = pp * 2;
        float lo = fmaf(w1[2 * k + 1], u1t[j], b1[k]);
        float hi = fmaf(w1[2 * k + 3], u1t[j], b1[k + 1]);
        Q1p[j * 36 + pp] = pkrtz(lo, hi);
    }
    for (int e = tid; e < 2048; e += 256)
        u0p[e] = u0g[n * 2048 + e];

    int wid = tid >> 6, lane = tid & 63, lr = lane & 15, g = lane >> 4;
    float b3v = b3[0];

    // A = W2 f16 fragments in registers (16 VGPRs), loaded from global
    half8 w2f[4][2];
    #pragma unroll
    for (int m = 0; m < 4; m++)
        #pragma unroll
        for (int s = 0; s < 2; s++)
            w2f[m][s] = __builtin_bit_cast(half8,
                *(const uint4*)&w2h[(m * 16 + lr) * 32 + s * 16 + g * 4]);
    __syncthreads();

    const half2v hz = {(_Float16)0, (_Float16)0};
    for (int ii = 0; ii < 8; ii++) {
        int ixl = wid * 8 + ii;
        #pragma unroll
        for (int nt = 0; nt < 4; nt++) {
            half2v u0v = h2(u0p[ixl * 64 + nt * 16 + lr]);
            const uint* q1p = &Q1p[(nt * 16 + lr) * 36];
            half8 bfr[2];
            #pragma unroll
            for (int s = 0; s < 2; s++) {
                uint4 q4 = *(const uint4*)&q1p[s * 16 + g * 4];
                uint4 wp4 = *(const uint4*)&w1ps[s * 16 + g * 4];
                half2v h0 = __builtin_elementwise_max(h2(wp4.x) * u0v + h2(q4.x), hz);
                half2v h1v = __builtin_elementwise_max(h2(wp4.y) * u0v + h2(q4.y), hz);
                half2v h2v_ = __builtin_elementwise_max(h2(wp4.z) * u0v + h2(q4.z), hz);
                half2v h3 = __builtin_elementwise_max(h2(wp4.w) * u0v + h2(q4.w), hz);
                uint4 hb = {__builtin_bit_cast(uint, h0), __builtin_bit_cast(uint, h1v),
                            __builtin_bit_cast(uint, h2v_), __builtin_bit_cast(uint, h3)};
                bfr[s] = __builtin_bit_cast(half8, hb);
            }
            f32x4 acc[4];
            #pragma unroll
            for (int m = 0; m < 4; m++) {
                f32x4 cseed = *(const f32x4*)&b2s[m * 16 + g * 4];
                acc[m] = __builtin_amdgcn_mfma_f32_16x16x32_f16(w2f[m][0], bfr[0], cseed, 0, 0, 0);
            }
            #pragma unroll
            for (int m = 0; m < 4; m++)
                acc[m] = __builtin_amdgcn_mfma_f32_16x16x32_f16(w2f[m][1], bfr[1], acc[m], 0, 0, 0);
            f32x4 tv = {0.f, 0.f, 0.f, 0.f};
            #pragma unroll
            for (int m = 0; m < 4; m++) {
                f32x4 r = __builtin_elementwise_max(acc[m], (f32x4){0.f, 0.f, 0.f, 0.f});
                f32x4 w3m = *(const f32x4*)&w3s[m * 16 + g * 4];
                tv += w3m * r;
            }
            float t = (tv[0] + tv[1]) + (tv[2] + tv[3]);
            t += __shfl_xor(t, 16);
            t += __shfl_xor(t, 32);
            if (g == nt) biasS[ixl * 68 + lane] = t + b3v;
        }
    }
    __syncthreads();

    // ---------------- fused attention (waves 0 and 1) ---------------------
    if (wid < 2) {
        int lb = wid * 16;                 // local row base
        float* P = &biasS[lb * 68];        // 16*68 scratch
        int i0w = iy * 32 + lb;
        const short* kb = kob + n * 4096;
        const short* vb = vob + n * 4096;
        const short* qb = qbt + ((size_t)n * 1024 + i0w + lr) * 64;
        short8b qf[2];
        qf[0] = *(const short8b*)&qb[g * 8];
        qf[1] = *(const short8b*)&qb[32 + g * 8];
        float bv[4][4];
        #pragma unroll
        for (int r = 0; r < 4; r++)
            #pragma unroll
            for (int nt = 0; nt < 4; nt++)
                bv[r][nt] = biasS[(lb + g * 4 + r) * 68 + nt * 16 + lr];

        f32x4 acc[4];
        #pragma unroll
        for (int nt = 0; nt < 4; nt++) {
            short8b kf0 = *(const short8b*)&kb[(nt * 16 + lr) * 64 + g * 8];
            short8b kf1 = *(const short8b*)&kb[(nt * 16 + lr) * 64 + 32 + g * 8];
            acc[nt] = (f32x4){0.f, 0.f, 0.f, 0.f};
            acc[nt] = __builtin_amdgcn_mfma_f32_16x16x32_bf16(qf[0], kf0, acc[nt], 0, 0, 0);
            acc[nt] = __builtin_amdgcn_mfma_f32_16x16x32_bf16(qf[1], kf1, acc[nt], 0, 0, 0);
        }
        #pragma unroll
        for (int r = 0; r < 4; r++) {
            float s0 = acc[0][r] + bv[r][0], s1 = acc[1][r] + bv[r][1];
            float s2 = acc[2][r] + bv[r][2], s3 = acc[3][r] + bv[r][3];
            float m = fmaxf(fmaxf(s0, s1), fmaxf(s2, s3));
            m = fmaxf(m, __shfl_xor(m, 1));
            m = fmaxf(m, __shfl_xor(m, 2));
            m = fmaxf(m, __shfl_xor(m, 4));
            m = fmaxf(m, __shfl_xor(m, 8));
            float e0 = __expf(s0 - m), e1 = __expf(s1 - m);
            float e2 = __expf(s2 - m), e3 = __expf(s3 - m);
            float sum = (e0 + e1) + (e2 + e3);
            sum += __shfl_xor(sum, 1);
            sum += __shfl_xor(sum, 2);
            sum += __shfl_xor(sum, 4);
            sum += __shfl_xor(sum, 8);
            float inv = 1.f / sum;
            int row = g * 4 + r;
            P[row * 68 + lr]      = e0 * inv;
            P[row * 68 + 16 + lr] = e1 * inv;
            P[row * 68 + 32 + lr] = e2 * inv;
            P[row * 68 + 48 + lr] = e3 * inv;
        }
        const float* pr = &P[lr * 68];
        float4 a0 = *(float4*)&pr[g * 8];
        float4 a1 = *(float4*)&pr[g * 8 + 4];
        float4 a2 = *(float4*)&pr[32 + g * 8];
        float4 a3 = *(float4*)&pr[32 + g * 8 + 4];
        uint4 up0 = {pack2(a0.x, a0.y), pack2(a0.z, a0.w), pack2(a1.x, a1.y), pack2(a1.z, a1.w)};
        uint4 up1 = {pack2(a2.x, a2.y), pack2(a2.z, a2.w), pack2(a3.x, a3.y), pack2(a3.z, a3.w)};
        short8b pf0 = __builtin_bit_cast(short8b, up0);
        short8b pf1 = __builtin_bit_cast(short8b, up1);

        f32x4 oacc[4];
        #pragma unroll
        for (int nt = 0; nt < 4; nt++) {
            short8b vf0 = *(const short8b*)&vb[(nt * 16 + lr) * 64 + g * 8];
            short8b vf1 = *(const short8b*)&vb[(nt * 16 + lr) * 64 + 32 + g * 8];
            oacc[nt] = (f32x4){0.f, 0.f, 0.f, 0.f};
            oacc[nt] = __builtin_amdgcn_mfma_f32_16x16x32_bf16(pf0, vf0, oacc[nt], 0, 0, 0);
            oacc[nt] = __builtin_amdgcn_mfma_f32_16x16x32_bf16(pf1, vf1, oacc[nt], 0, 0, 0);
        }
        #pragma unroll
        for (int nt = 0; nt < 4; nt++)
            #pragma unroll
            for (int r = 0; r < 4; r++)
                P[(nt * 16 + lr) * 17 + g * 4 + r] = oacc[nt][r];
        int il = lane >> 2, dq = lane & 3;
        uint ub[8];
        #pragma unroll
        for (int t = 0; t < 8; t++) {
            float lo = P[(dq * 16 + 2 * t) * 17 + il];
            float hi = P[(dq * 16 + 2 * t + 1) * 17 + il];
            ub[t] = pack2(lo, hi);
        }
        int b_ = n >> 2, h_ = n & 3;
        short* op = attb + ((size_t)(b_ * 1024 + i0w + il)) * 256 + h_ * 64 + dq * 16;
        uint4 s0v = {ub[0], ub[1], ub[2], ub[3]};
        uint4 s1v = {ub[4], ub[5], ub[6], ub[7]};
        ((uint4*)op)[0] = s0v;
        ((uint4*)op)[1] = s1v;
    }
}

// ------------- output projection via MFMA: C[(b,hw)][co], K=256 -----------
__global__ __launch_bounds__(256) void k_outproj(const short* __restrict__ attb,
                                                 const short* __restrict__ wob,
                                                 const float* __restrict__ bout,
                                                 float* __restrict__ y) {
    int rt = blockIdx.x;             // 256: b = rt>>5, hw-tile of 32
    int ct = blockIdx.y;             // 2
    int tid = threadIdx.x, wid = tid >> 6, lane = tid & 63, lr = lane & 15, g = lane >> 4;
    int wr = wid >> 1, wc = wid & 1;
    int b = rt >> 5;
    int hw0 = (rt & 31) * 32 + wr * 16;
    int cobase = ct * 128 + wc * 64;
    const short* arow = attb + ((size_t)(b * 1024) + hw0) * 256;
    const short* brow = wob + (size_t)cobase * 256;

    f32x4 acc[4];
    #pragma unroll
    for (int nn = 0; nn < 4; nn++) acc[nn] = (f32x4){0.f, 0.f, 0.f, 0.f};
    #pragma unroll
    for (int s = 0; s < 8; s++) {
        short8b af = *(const short8b*)&arow[lr * 256 + s * 32 + g * 8];
        #pragma unroll
        for (int nn = 0; nn < 4; nn++) {
            short8b bf = *(const short8b*)&brow[(nn * 16 + lr) * 256 + s * 32 + g * 8];
            acc[nn] = __builtin_amdgcn_mfma_f32_16x16x32_bf16(af, bf, acc[nn], 0, 0, 0);
        }
    }
    #pragma unroll
    for (int nn = 0; nn < 4; nn++) {
        int co = cobase + nn * 16 + lr;
        float bo = bout[co];
        float4 o = {acc[nn][0] + bo, acc[nn][1] + bo, acc[nn][2] + bo, acc[nn][3] + bo};
        *(float4*)&y[(size_t)b * 262144 + (size_t)co * 1024 + hw0 + g * 4] = o;
    }
}

extern "C" void kernel_launch(void* const* d_in, const int* in_sizes, int n_in,
                              void* d_out, int out_size, void* d_ws, size_t ws_size,
                              hipStream_t stream) {
    const float* x    = (const float*)d_in[0];
    const float* wq   = (const float*)d_in[1];
    const float* wk   = (const float*)d_in[2];
    const float* wv   = (const float*)d_in[3];
    const float* wdw  = (const float*)d_in[4];
    const float* bdw  = (const float*)d_in[5];
    const float* wpw  = (const float*)d_in[6];
    const float* cw1  = (const float*)d_in[7];
    const float* cb1  = (const float*)d_in[8];
    const float* cw2  = (const float*)d_in[9];
    const float* cb2  = (const float*)d_in[10];
    const float* cw3  = (const float*)d_in[11];
    const float* cb3  = (const float*)d_in[12];
    const float* wout = (const float*)d_in[13];
    const float* bout = (const float*)d_in[14];
    float* y  = (float*)d_out;
    float* ws = (float*)d_ws;

    float* q    = ws;                          // 8MB f32 (dead after k_dw)
    short* attb = (short*)ws;                  // alias: bf16 attn out [b*hw][ci]
    float* vgs  = ws + 4325376;
    short* qbt  = (short*)(ws + 4329472);
    short* kob  = (short*)(ws + 5378048);
    short* vob  = (short*)(ws + 5443584);
    float* gdw  = ws + 5509120;
    short* wob  = (short*)(ws + 5640192);      // 65536 bf16
    uint*  u0g  = (uint*)(ws + 5672960);       // 65536 uint (f16x2 u0 table)
    uint*  w2h  = (uint*)(ws + 5738496);       // 2048 uint (f16x2 W2)

    k_qproj  <<<dim3(8, 4, 8),  256, 0, stream>>>(x, wq, q, qbt);
    k_dw     <<<dim3(8, 32),    256, 0, stream>>>(q, wdw, bdw, gdw);
    k_pre    <<<32,             256, 0, stream>>>(x, gdw, wpw, wk, wv, wout, cw2,
                                                  vgs, u0g, kob, vob, wob, w2h);
    k_cpb    <<<dim3(32, 32),   256, 0, stream>>>(vgs, u0g, cw1, cb1, w2h, cb2, cw3, cb3,
                                                  qbt, kob, vob, attb);
    k_outproj<<<dim3(256, 2),   256, 0, stream>>>(attb, wob, bout, y);
}

// Round 18
// 83.599 us; speedup vs baseline: 1.2566x; 1.1442x over previous
//
#include <hip/hip_runtime.h>
#include <hip/hip_bf16.h>
#include <math.h>

#define QSCALE 0.125f

typedef __attribute__((ext_vector_type(8))) short short8b;   // 8 bf16 (4 VGPRs)
typedef __attribute__((ext_vector_type(8))) _Float16 half8;  // 8 f16  (4 VGPRs)
typedef __attribute__((ext_vector_type(2))) _Float16 half2v; // f16x2 (1 VGPR)
typedef __attribute__((ext_vector_type(4))) float f32x4;

__device__ __forceinline__ uint pack2(float a, float b) {
    uint r;
    asm("v_cvt_pk_bf16_f32 %0, %1, %2" : "=v"(r) : "v"(a), "v"(b));
    return r;
}
__device__ __forceinline__ uint pkrtz(float a, float b) {
    uint r;
    asm("v_cvt_pkrtz_f16_f32 %0, %1, %2" : "=v"(r) : "v"(a), "v"(b));
    return r;
}
__device__ __forceinline__ half2v h2(uint u) { return __builtin_bit_cast(half2v, u); }
__device__ __forceinline__ float slogf_(float p) {
    return copysignf(log1pf(fabsf(p)), p);
}

// ------- q projection via MFMA + wout bf16 convert ------------------------
__global__ __launch_bounds__(256) void k_qproj(const float* __restrict__ x,
                                               const float* __restrict__ wq,
                                               const float* __restrict__ wout,
                                               float* __restrict__ q,
                                               short* __restrict__ qbt,
                                               short* __restrict__ wob) {
    __shared__ uint wqh[64 * 36];    // [co][ci/2] f16 pairs
    __shared__ uint xsT[128 * 36];   // [hw][ci/2] f16 pairs
    int ht = blockIdx.x, g = blockIdx.y, b = blockIdx.z;
    int tid = threadIdx.x;
    // wout cvt: 32768 pairs over 256 blocks
    {
        int bid = (blockIdx.z * 4 + blockIdx.y) * 8 + blockIdx.x;
        if (tid < 128) {
            int idx = bid * 128 + tid;
            float2 w = *(const float2*)&wout[idx * 2];
            *(uint*)&wob[idx * 2] = pack2(w.x, w.y);
        }
    }
    for (int e = tid; e < 2048; e += 256) {
        int co = e >> 5, p = e & 31;
        float2 w2v = *(const float2*)&wq[(g * 64 + co) * 64 + 2 * p];
        wqh[co * 36 + p] = pkrtz(w2v.x, w2v.y);
    }
    const float* xb = x + (b * 256 + g * 64) * 1024 + ht * 128;
    for (int e = tid; e < 4096; e += 256) {
        int p = e >> 7, hw = e & 127;
        float lo = xb[(2 * p) * 1024 + hw];
        float hi = xb[(2 * p + 1) * 1024 + hw];
        xsT[hw * 36 + p] = pkrtz(lo, hi);
    }
    __syncthreads();
    int wid = tid >> 6, lane = tid & 63, lr = lane & 15, g4 = lane >> 4;
    half8 af[4][2];
    #pragma unroll
    for (int m = 0; m < 4; m++)
        #pragma unroll
        for (int s = 0; s < 2; s++)
            af[m][s] = __builtin_bit_cast(half8,
                *(const uint4*)&wqh[(m * 16 + lr) * 36 + s * 16 + g4 * 4]);
    f32x4 acc[4][2];
    #pragma unroll
    for (int m = 0; m < 4; m++)
        #pragma unroll
        for (int nt = 0; nt < 2; nt++) acc[m][nt] = (f32x4){0.f, 0.f, 0.f, 0.f};
    #pragma unroll
    for (int s = 0; s < 2; s++)
        #pragma unroll
        for (int nt = 0; nt < 2; nt++) {
            half8 bf = __builtin_bit_cast(half8,
                *(const uint4*)&xsT[(wid * 32 + nt * 16 + lr) * 36 + s * 16 + g4 * 4]);
            #pragma unroll
            for (int m = 0; m < 4; m++)
                acc[m][nt] = __builtin_amdgcn_mfma_f32_16x16x32_f16(af[m][s], bf, acc[m][nt], 0, 0, 0);
        }
    float* qb = q + (b * 256 + g * 64) * 1024 + ht * 128;
    #pragma unroll
    for (int m = 0; m < 4; m++)
        #pragma unroll
        for (int nt = 0; nt < 2; nt++) {
            int hw = wid * 32 + nt * 16 + lr;
            #pragma unroll
            for (int r = 0; r < 4; r++)
                qb[(m * 16 + g4 * 4 + r) * 1024 + hw] = acc[m][nt][r];
        }
    short* q16 = qbt + ((size_t)((b * 4 + g) * 1024 + ht * 128)) * 64;
    #pragma unroll
    for (int nt = 0; nt < 2; nt++) {
        int hw = wid * 32 + nt * 16 + lr;
        #pragma unroll
        for (int m = 0; m < 4; m++) {
            uint2 uu;
            uu.x = pack2(acc[m][nt][0] * QSCALE, acc[m][nt][1] * QSCALE);
            uu.y = pack2(acc[m][nt][2] * QSCALE, acc[m][nt][3] * QSCALE);
            *(uint2*)&q16[hw * 64 + m * 16 + g4 * 4] = uu;
        }
    }
}

// --------- offsets stage 1: depthwise conv6x6 s4 p1 + GELU ---------------
__global__ __launch_bounds__(256) void k_dw(const float* __restrict__ q,
                                            const float* __restrict__ wdw,
                                            const float* __restrict__ bdw,
                                            float* __restrict__ gdw) {
    __shared__ float qs[8 * 1024];
    __shared__ float wds[8 * 36];
    int cg = blockIdx.x, n = blockIdx.y;
    int b = n >> 2, gg = n & 3;
    int c0 = cg * 8;
    int tid = threadIdx.x;
    const float* qn = q + (b * 256 + gg * 64 + c0) * 1024;
    for (int e = tid; e < 2048; e += 256)
        ((float4*)qs)[e] = ((const float4*)qn)[e];
    for (int e = tid; e < 288; e += 256)
        wds[e] = wdw[c0 * 36 + e];
    __syncthreads();
    for (int e = tid; e < 512; e += 256) {
        int c = e >> 6, pos = e & 63;
        int oy = pos >> 3, ox = pos & 7;
        float acc = bdw[c0 + c];
        #pragma unroll
        for (int ky = 0; ky < 6; ky++) {
            int iy = oy * 4 - 1 + ky;
            if (iy < 0 || iy > 31) continue;
            #pragma unroll
            for (int kx = 0; kx < 6; kx++) {
                int ix = ox * 4 - 1 + kx;
                if (ix < 0 || ix > 31) continue;
                acc += qs[c * 1024 + iy * 32 + ix] * wds[c * 36 + ky * 6 + kx];
            }
        }
        gdw[(n * 64 + c0 + c) * 64 + pos] = acc * 0.5f * (1.f + erff(acc * 0.70710678118654752f));
    }
}

// ---- pre, 4x split: per (quarter, n): pw + u0 + sample + MFMA kvproj -----
__global__ __launch_bounds__(256) void k_pre(const float* __restrict__ x,
                                             const float* __restrict__ gdw,
                                             const float* __restrict__ wpw,
                                             const float* __restrict__ wk,
                                             const float* __restrict__ wv,
                                             const float* __restrict__ w2,
                                             float* __restrict__ vgs,
                                             uint* __restrict__ u0g,
                                             short* __restrict__ kob,
                                             short* __restrict__ vob,
                                             uint* __restrict__ w2h) {
    __shared__ float gq[64 * 16];    // gdw slice [c][p]
    __shared__ float kvsT[16 * 68];  // sampled kv [p][ci]
    __shared__ uint wkh[64 * 36];    // wk f16 pairs [co][ci/2]
    __shared__ uint wvh[64 * 36];
    __shared__ uint kvh[16 * 36];    // kv f16 pairs [p][ci/2]
    __shared__ float vx_s[16], vy_s[16];
    int qt = blockIdx.x, n = blockIdx.y, tid = threadIdx.x;
    int b = n >> 2, g = n & 3;
    int p0 = qt * 16;

    // w2 f32 -> f16 pairs (qt 0 only; 64 entries per n, total 2048)
    if (qt == 0 && tid < 64) {
        int idx = n * 64 + tid;
        int c2 = idx >> 5, p = idx & 31;
        float2 wv2 = *(const float2*)&w2[c2 * 64 + 2 * p];
        w2h[c2 * 32 + p] = pkrtz(wv2.x, wv2.y);
    }
    // stage wk/wv f16 pairs
    for (int e = tid; e < 2048; e += 256) {
        int co = e >> 5, p = e & 31;
        float2 a = *(const float2*)&wk[(g * 64 + co) * 64 + 2 * p];
        float2 c = *(const float2*)&wv[(g * 64 + co) * 64 + 2 * p];
        wkh[co * 36 + p] = pkrtz(a.x, a.y);
        wvh[co * 36 + p] = pkrtz(c.x, c.y);
    }
    // stage gdw slice [c][p] (64B contiguous per c)
    for (int e = tid; e < 1024; e += 256) {
        int c = e >> 4, p = e & 15;
        gq[c * 16 + p] = gdw[n * 4096 + c * 64 + p0 + p];
    }
    __syncthreads();
    // pw conv + tanh -> grid coords for this quarter
    if (tid < 32) {
        int o = tid >> 4, p = tid & 15;
        float a = 0.f;
        #pragma unroll 8
        for (int c = 0; c < 64; c++) a += gq[c * 16 + p] * wpw[o * 64 + c];
        float off = tanhf(a) * 4.0f;
        int pos = p0 + p;
        if (o == 0) {
            int ox = pos & 7;
            float v = 2.f * ((float)ox + off) / 7.f - 1.f;
            vx_s[p] = v;
            vgs[(n * 64 + pos) * 2] = v;
        } else {
            int oy = pos >> 3;
            float v = 2.f * ((float)oy + off) / 7.f - 1.f;
            vy_s[p] = v;
            vgs[(n * 64 + pos) * 2 + 1] = v;
        }
    }
    __syncthreads();
    // u0 table: all 32 ix, j in quarter
    for (int e = tid; e < 512; e += 256) {
        int ix = e >> 4, j = e & 15;
        float qx = (2.f / 31.f) * (float)ix - 1.f;
        float u = slogf_(qx - vx_s[j]);
        u0g[n * 2048 + ix * 64 + p0 + j] = pkrtz(u, u);
    }
    // bilinear sample: 64 c x 16 p
    for (int e = tid; e < 1024; e += 256) {
        int c = e >> 4, p = e & 15;
        float ix = (vx_s[p] + 1.f) * 16.f - 0.5f;
        float iy = (vy_s[p] + 1.f) * 16.f - 0.5f;
        float x0 = floorf(ix), y0 = floorf(iy);
        float wa = (x0 + 1.f - ix) * (y0 + 1.f - iy);
        float wb = (ix - x0) * (y0 + 1.f - iy);
        float wc = (x0 + 1.f - ix) * (iy - y0);
        float wd = (ix - x0) * (iy - y0);
        const float* img = x + (b * 256 + g * 64 + c) * 1024;
        int xi = (int)x0, yi = (int)y0;
        float acc = 0.f;
        if (xi >= 0 && xi <= 31 && yi >= 0 && yi <= 31)             acc += img[yi * 32 + xi] * wa;
        if (xi + 1 >= 0 && xi + 1 <= 31 && yi >= 0 && yi <= 31)     acc += img[yi * 32 + xi + 1] * wb;
        if (xi >= 0 && xi <= 31 && yi + 1 >= 0 && yi + 1 <= 31)     acc += img[(yi + 1) * 32 + xi] * wc;
        if (xi + 1 >= 0 && xi + 1 <= 31 && yi + 1 >= 0 && yi + 1 <= 31) acc += img[(yi + 1) * 32 + xi + 1] * wd;
        kvsT[p * 68 + c] = acc;
    }
    __syncthreads();
    // kv f16 pairs
    for (int e = tid; e < 512; e += 256) {
        int p = e >> 5, pp = e & 31;
        float2 v2 = *(const float2*)&kvsT[p * 68 + 2 * pp];
        kvh[p * 36 + pp] = pkrtz(v2.x, v2.y);
    }
    __syncthreads();
    // MFMA kvproj: wave -> matrix (wid>>1), co half (wid&1)*32; j tile = lr
    int wid = tid >> 6, lane = tid & 63, lr = lane & 15, gq4 = lane >> 4;
    int mat = wid >> 1, cb = (wid & 1) * 32;
    const uint* wh = mat ? wvh : wkh;
    half8 bf[2];
    #pragma unroll
    for (int s = 0; s < 2; s++)
        bf[s] = __builtin_bit_cast(half8, *(const uint4*)&kvh[lr * 36 + s * 16 + gq4 * 4]);
    #pragma unroll
    for (int ct2 = 0; ct2 < 2; ct2++) {
        int ct = cb + ct2 * 16;
        half8 af[2];
        #pragma unroll
        for (int s = 0; s < 2; s++)
            af[s] = __builtin_bit_cast(half8, *(const uint4*)&wh[(ct + lr) * 36 + s * 16 + gq4 * 4]);
        f32x4 acc = {0.f, 0.f, 0.f, 0.f};
        acc = __builtin_amdgcn_mfma_f32_16x16x32_f16(af[0], bf[0], acc, 0, 0, 0);
        acc = __builtin_amdgcn_mfma_f32_16x16x32_f16(af[1], bf[1], acc, 0, 0, 0);
        if (mat == 0) {
            uint2 uu = {pack2(acc[0], acc[1]), pack2(acc[2], acc[3])};
            *(uint2*)&kob[n * 4096 + (p0 + lr) * 64 + ct + gq4 * 4] = uu;
        } else {
            #pragma unroll
            for (int r = 0; r < 4; r++)
                vob[n * 4096 + (ct + gq4 * 4 + r) * 64 + p0 + lr] = (short)pack2(acc[r], acc[r]);
        }
    }
}

// ---- CPB bias MLP + fused attention. Block (iy,n), 256 thr / 4 waves. ----
__global__ __launch_bounds__(256) void k_cpb(const float* __restrict__ vgs,
                                             const uint* __restrict__ u0g,
                                             const float* __restrict__ w1,
                                             const float* __restrict__ b1,
                                             const uint* __restrict__ w2h,
                                             const float* __restrict__ b2,
                                             const float* __restrict__ w3,
                                             const float* __restrict__ b3,
                                             const short* __restrict__ qbt,
                                             const short* __restrict__ kob,
                                             const short* __restrict__ vob,
                                             short* __restrict__ attb) {
    __shared__ uint Q1p[64 * 36];    // [j][k-pair] f16x2, stride 36
    __shared__ uint u0p[32 * 64];    // [ix][j] f16x2 (full iy row)
    __shared__ float u1t[64];
    __shared__ uint w1ps[32];
    __shared__ float w3s[64];
    __shared__ float b2s[64];
    __shared__ float biasS[32 * 68]; // bias [ix][j]; halves reused as attn scratch
    int iy = blockIdx.x, n = blockIdx.y, tid = threadIdx.x;
    float qy = 2.f * (float)iy / 31.f - 1.f;

    if (tid < 64) u1t[tid] = slogf_(qy - vgs[(n << 7) + tid * 2 + 1]);
    if (tid >= 64 && tid < 96) {
        int p = tid - 64;
        int s = p >> 4, gg = (p >> 2) & 3, pp = p & 3;
        int k = s * 32 + gg * 8 + 2 * pp;
        w1ps[p] = pkrtz(w1[2 * k], w1[2 * k + 2]);
    }
    if (tid >= 128 && tid < 192) w3s[tid - 128] = w3[tid - 128];
    if (tid >= 192) b2s[tid - 192] = b2[tid - 192];
    __syncthreads();
    for (int e = tid; e < 2048; e += 256) {
        int j = e >> 5, pp = e & 31;
        int k = pp * 2;
        float lo = fmaf(w1[2 * k + 1], u1t[j], b1[k]);
        float hi = fmaf(w1[2 * k + 3], u1t[j], b1[k + 1]);
        Q1p[j * 36 + pp] = pkrtz(lo, hi);
    }
    for (int e = tid; e < 2048; e += 256)
        u0p[e] = u0g[n * 2048 + e];

    int wid = tid >> 6, lane = tid & 63, lr = lane & 15, g = lane >> 4;
    float b3v = b3[0];

    half8 w2f[4][2];
    #pragma unroll
    for (int m = 0; m < 4; m++)
        #pragma unroll
        for (int s = 0; s < 2; s++)
            w2f[m][s] = __builtin_bit_cast(half8,
                *(const uint4*)&w2h[(m * 16 + lr) * 32 + s * 16 + g * 4]);
    __syncthreads();

    const half2v hz = {(_Float16)0, (_Float16)0};
    for (int ii = 0; ii < 8; ii++) {
        int ixl = wid * 8 + ii;
        #pragma unroll
        for (int nt = 0; nt < 4; nt++) {
            half2v u0v = h2(u0p[ixl * 64 + nt * 16 + lr]);
            const uint* q1p = &Q1p[(nt * 16 + lr) * 36];
            half8 bfr[2];
            #pragma unroll
            for (int s = 0; s < 2; s++) {
                uint4 q4 = *(const uint4*)&q1p[s * 16 + g * 4];
                uint4 wp4 = *(const uint4*)&w1ps[s * 16 + g * 4];
                half2v h0 = __builtin_elementwise_max(h2(wp4.x) * u0v + h2(q4.x), hz);
                half2v h1v = __builtin_elementwise_max(h2(wp4.y) * u0v + h2(q4.y), hz);
                half2v h2v_ = __builtin_elementwise_max(h2(wp4.z) * u0v + h2(q4.z), hz);
                half2v h3 = __builtin_elementwise_max(h2(wp4.w) * u0v + h2(q4.w), hz);
                uint4 hb = {__builtin_bit_cast(uint, h0), __builtin_bit_cast(uint, h1v),
                            __builtin_bit_cast(uint, h2v_), __builtin_bit_cast(uint, h3)};
                bfr[s] = __builtin_bit_cast(half8, hb);
            }
            f32x4 acc[4];
            #pragma unroll
            for (int m = 0; m < 4; m++) {
                f32x4 cseed = *(const f32x4*)&b2s[m * 16 + g * 4];
                acc[m] = __builtin_amdgcn_mfma_f32_16x16x32_f16(w2f[m][0], bfr[0], cseed, 0, 0, 0);
            }
            #pragma unroll
            for (int m = 0; m < 4; m++)
                acc[m] = __builtin_amdgcn_mfma_f32_16x16x32_f16(w2f[m][1], bfr[1], acc[m], 0, 0, 0);
            f32x4 tv = {0.f, 0.f, 0.f, 0.f};
            #pragma unroll
            for (int m = 0; m < 4; m++) {
                f32x4 r = __builtin_elementwise_max(acc[m], (f32x4){0.f, 0.f, 0.f, 0.f});
                f32x4 w3m = *(const f32x4*)&w3s[m * 16 + g * 4];
                tv += w3m * r;
            }
            float t = (tv[0] + tv[1]) + (tv[2] + tv[3]);
            t += __shfl_xor(t, 16);
            t += __shfl_xor(t, 32);
            if (g == nt) biasS[ixl * 68 + lane] = t + b3v;
        }
    }
    __syncthreads();

    // ---------------- fused attention (waves 0 and 1) ---------------------
    if (wid < 2) {
        int lb = wid * 16;                 // local row base
        float* P = &biasS[lb * 68];        // 16*68 scratch
        int i0w = iy * 32 + lb;
        const short* kb = kob + n * 4096;
        const short* vb = vob + n * 4096;
        const short* qb = qbt + ((size_t)n * 1024 + i0w + lr) * 64;
        short8b qf[2];
        qf[0] = *(const short8b*)&qb[g * 8];
        qf[1] = *(const short8b*)&qb[32 + g * 8];
        float bv[4][4];
        #pragma unroll
        for (int r = 0; r < 4; r++)
            #pragma unroll
            for (int nt = 0; nt < 4; nt++)
                bv[r][nt] = biasS[(lb + g * 4 + r) * 68 + nt * 16 + lr];

        f32x4 acc[4];
        #pragma unroll
        for (int nt = 0; nt < 4; nt++) {
            short8b kf0 = *(const short8b*)&kb[(nt * 16 + lr) * 64 + g * 8];
            short8b kf1 = *(const short8b*)&kb[(nt * 16 + lr) * 64 + 32 + g * 8];
            acc[nt] = (f32x4){0.f, 0.f, 0.f, 0.f};
            acc[nt] = __builtin_amdgcn_mfma_f32_16x16x32_bf16(qf[0], kf0, acc[nt], 0, 0, 0);
            acc[nt] = __builtin_amdgcn_mfma_f32_16x16x32_bf16(qf[1], kf1, acc[nt], 0, 0, 0);
        }
        #pragma unroll
        for (int r = 0; r < 4; r++) {
            float s0 = acc[0][r] + bv[r][0], s1 = acc[1][r] + bv[r][1];
            float s2 = acc[2][r] + bv[r][2], s3 = acc[3][r] + bv[r][3];
            float m = fmaxf(fmaxf(s0, s1), fmaxf(s2, s3));
            m = fmaxf(m, __shfl_xor(m, 1));
            m = fmaxf(m, __shfl_xor(m, 2));
            m = fmaxf(m, __shfl_xor(m, 4));
            m = fmaxf(m, __shfl_xor(m, 8));
            float e0 = __expf(s0 - m), e1 = __expf(s1 - m);
            float e2 = __expf(s2 - m), e3 = __expf(s3 - m);
            float sum = (e0 + e1) + (e2 + e3);
            sum += __shfl_xor(sum, 1);
            sum += __shfl_xor(sum, 2);
            sum += __shfl_xor(sum, 4);
            sum += __shfl_xor(sum, 8);
            float inv = 1.f / sum;
            int row = g * 4 + r;
            P[row * 68 + lr]      = e0 * inv;
            P[row * 68 + 16 + lr] = e1 * inv;
            P[row * 68 + 32 + lr] = e2 * inv;
            P[row * 68 + 48 + lr] = e3 * inv;
        }
        const float* pr = &P[lr * 68];
        float4 a0 = *(float4*)&pr[g * 8];
        float4 a1 = *(float4*)&pr[g * 8 + 4];
        float4 a2 = *(float4*)&pr[32 + g * 8];
        float4 a3 = *(float4*)&pr[32 + g * 8 + 4];
        uint4 up0 = {pack2(a0.x, a0.y), pack2(a0.z, a0.w), pack2(a1.x, a1.y), pack2(a1.z, a1.w)};
        uint4 up1 = {pack2(a2.x, a2.y), pack2(a2.z, a2.w), pack2(a3.x, a3.y), pack2(a3.z, a3.w)};
        short8b pf0 = __builtin_bit_cast(short8b, up0);
        short8b pf1 = __builtin_bit_cast(short8b, up1);

        f32x4 oacc[4];
        #pragma unroll
        for (int nt = 0; nt < 4; nt++) {
            short8b vf0 = *(const short8b*)&vb[(nt * 16 + lr) * 64 + g * 8];
            short8b vf1 = *(const short8b*)&vb[(nt * 16 + lr) * 64 + 32 + g * 8];
            oacc[nt] = (f32x4){0.f, 0.f, 0.f, 0.f};
            oacc[nt] = __builtin_amdgcn_mfma_f32_16x16x32_bf16(pf0, vf0, oacc[nt], 0, 0, 0);
            oacc[nt] = __builtin_amdgcn_mfma_f32_16x16x32_bf16(pf1, vf1, oacc[nt], 0, 0, 0);
        }
        #pragma unroll
        for (int nt = 0; nt < 4; nt++)
            #pragma unroll
            for (int r = 0; r < 4; r++)
                P[(nt * 16 + lr) * 17 + g * 4 + r] = oacc[nt][r];
        int il = lane >> 2, dq = lane & 3;
        uint ub[8];
        #pragma unroll
        for (int t = 0; t < 8; t++) {
            float lo = P[(dq * 16 + 2 * t) * 17 + il];
            float hi = P[(dq * 16 + 2 * t + 1) * 17 + il];
            ub[t] = pack2(lo, hi);
        }
        int b_ = n >> 2, h_ = n & 3;
        short* op = attb + ((size_t)(b_ * 1024 + i0w + il)) * 256 + h_ * 64 + dq * 16;
        uint4 s0v = {ub[0], ub[1], ub[2], ub[3]};
        uint4 s1v = {ub[4], ub[5], ub[6], ub[7]};
        ((uint4*)op)[0] = s0v;
        ((uint4*)op)[1] = s1v;
    }
}

// ------------- output projection via MFMA: C[(b,hw)][co], K=256 -----------
__global__ __launch_bounds__(256) void k_outproj(const short* __restrict__ attb,
                                                 const short* __restrict__ wob,
                                                 const float* __restrict__ bout,
                                                 float* __restrict__ y) {
    int rt = blockIdx.x;             // 256: b = rt>>5, hw-tile of 32
    int ct = blockIdx.y;             // 2
    int tid = threadIdx.x, wid = tid >> 6, lane = tid & 63, lr = lane & 15, g = lane >> 4;
    int wr = wid >> 1, wc = wid & 1;
    int b = rt >> 5;
    int hw0 = (rt & 31) * 32 + wr * 16;
    int cobase = ct * 128 + wc * 64;
    const short* arow = attb + ((size_t)(b * 1024) + hw0) * 256;
    const short* brow = wob + (size_t)cobase * 256;

    f32x4 acc[4];
    #pragma unroll
    for (int nn = 0; nn < 4; nn++) acc[nn] = (f32x4){0.f, 0.f, 0.f, 0.f};
    #pragma unroll
    for (int s = 0; s < 8; s++) {
        short8b af = *(const short8b*)&arow[lr * 256 + s * 32 + g * 8];
        #pragma unroll
        for (int nn = 0; nn < 4; nn++) {
            short8b bf = *(const short8b*)&brow[(nn * 16 + lr) * 256 + s * 32 + g * 8];
            acc[nn] = __builtin_amdgcn_mfma_f32_16x16x32_bf16(af, bf, acc[nn], 0, 0, 0);
        }
    }
    #pragma unroll
    for (int nn = 0; nn < 4; nn++) {
        int co = cobase + nn * 16 + lr;
        float bo = bout[co];
        float4 o = {acc[nn][0] + bo, acc[nn][1] + bo, acc[nn][2] + bo, acc[nn][3] + bo};
        *(float4*)&y[(size_t)b * 262144 + (size_t)co * 1024 + hw0 + g * 4] = o;
    }
}

extern "C" void kernel_launch(void* const* d_in, const int* in_sizes, int n_in,
                              void* d_out, int out_size, void* d_ws, size_t ws_size,
                              hipStream_t stream) {
    const float* x    = (const float*)d_in[0];
    const float* wq   = (const float*)d_in[1];
    const float* wk   = (const float*)d_in[2];
    const float* wv   = (const float*)d_in[3];
    const float* wdw  = (const float*)d_in[4];
    const float* bdw  = (const float*)d_in[5];
    const float* wpw  = (const float*)d_in[6];
    const float* cw1  = (const float*)d_in[7];
    const float* cb1  = (const float*)d_in[8];
    const float* cw2  = (const float*)d_in[9];
    const float* cb2  = (const float*)d_in[10];
    const float* cw3  = (const float*)d_in[11];
    const float* cb3  = (const float*)d_in[12];
    const float* wout = (const float*)d_in[13];
    const float* bout = (const float*)d_in[14];
    float* y  = (float*)d_out;
    float* ws = (float*)d_ws;

    float* q    = ws;                          // 8MB f32 (dead after k_dw)
    short* attb = (short*)ws;                  // alias: bf16 attn out [b*hw][ci]
    float* vgs  = ws + 4325376;
    short* qbt  = (short*)(ws + 4329472);
    short* kob  = (short*)(ws + 5378048);
    short* vob  = (short*)(ws + 5443584);
    float* gdw  = ws + 5509120;
    short* wob  = (short*)(ws + 5640192);      // 65536 bf16
    uint*  u0g  = (uint*)(ws + 5672960);       // 65536 uint (f16x2 u0 table)
    uint*  w2h  = (uint*)(ws + 5738496);       // 2048 uint (f16x2 W2)

    k_qproj  <<<dim3(8, 4, 8),  256, 0, stream>>>(x, wq, wout, q, qbt, wob);
    k_dw     <<<dim3(8, 32),    256, 0, stream>>>(q, wdw, bdw, gdw);
    k_pre    <<<dim3(4, 32),    256, 0, stream>>>(x, gdw, wpw, wk, wv, cw2,
                                                  vgs, u0g, kob, vob, w2h);
    k_cpb    <<<dim3(32, 32),   256, 0, stream>>>(vgs, u0g, cw1, cb1, w2h, cb2, cw3, cb3,
                                                  qbt, kob, vob, attb);
    k_outproj<<<dim3(256, 2),   256, 0, stream>>>(attb, wob, bout, y);
}